// Round 8
// baseline (1439.833 us; speedup 1.0000x reference)
//
#include <hip/hip_runtime.h>
#include <stdint.h>

typedef unsigned short u16;
typedef float f32x4 __attribute__((ext_vector_type(4)));
typedef short bf16x8 __attribute__((ext_vector_type(8)));

// ---------- helpers ----------
__device__ __forceinline__ u16 f2bu(float f) {           // fp32 -> bf16 (RNE)
  uint32_t x = __builtin_bit_cast(uint32_t, f);
  x += 0x7fffu + ((x >> 16) & 1u);
  return (u16)(x >> 16);
}
__device__ __forceinline__ float b2f(u16 u) {            // bf16 -> fp32 (exact)
  return __builtin_bit_cast(float, (uint32_t)u << 16);
}
__device__ __forceinline__ void gll16(const void* g, void* l) {
  __builtin_amdgcn_global_load_lds(
      (const __attribute__((address_space(1))) void*)g,
      (__attribute__((address_space(3))) void*)l, 16, 0, 0);
}
#define MEMFENCE asm volatile("" ::: "memory")
#define BAR() do { __builtin_amdgcn_s_barrier(); MEMFENCE; } while (0)

// ---------- fp32 -> bf16 convert ----------
__global__ __launch_bounds__(256) void cvt_f32_bf16_kernel(
    const float* __restrict__ in, u16* __restrict__ out, int n4) {
  int i = blockIdx.x * 256 + threadIdx.x;
  const int stride = gridDim.x * 256;
  for (; i < n4; i += stride) {
    float4 f = reinterpret_cast<const float4*>(in)[i];
    ushort4 o;
    o.x = f2bu(f.x); o.y = f2bu(f.y); o.z = f2bu(f.z); o.w = f2bu(f.w);
    reinterpret_cast<ushort4*>(out)[i] = o;
  }
}

// ---------- GEMM1: 256x256, BK=64, 2 buf, 4 quadrant phases (r7 best) ----------
__global__ __launch_bounds__(512, 2) void gemm256_bt_bias(
    const u16* __restrict__ A, const u16* __restrict__ Bw,
    const float* __restrict__ bias, u16* __restrict__ C,
    int N, int K, int ntn) {
  __shared__ u16 lds[2][2][2][8192];   // [buf][A=0/B=1][khalf][256*32]
  const int tid = threadIdx.x;
  const int lane = tid & 63, wid = tid >> 6;
  const int wr = wid >> 2, wc = wid & 3;        // wave grid 2 (M) x 4 (N)
  const int fr = lane & 15, kg = lane >> 4;

  const int cpx = (int)gridDim.x >> 3;
  const int bid = blockIdx.x;
  const int sid = (bid & 7) * cpx + (bid >> 3);
  const int mt = sid / ntn, nt = sid % ntn;

  const int srow = tid >> 2;
  const int scol = (tid & 3) ^ ((tid >> 3) & 3);
  const u16* Ag = A + (size_t)(mt * 256 + srow) * K + scol * 8;
  const u16* Bg = Bw + (size_t)(nt * 256 + srow) * K + scol * 8;
  const size_t rstep = (size_t)128 * K;

  const int sw = (fr >> 1) & 3;
  const int kgs = (kg ^ sw) * 8;
  const int aoff = (wr * 128 + fr) * 32 + kgs;
  const int boff = (wc * 64 + fr) * 32 + kgs;

  f32x4 acc[8][4];
#pragma unroll
  for (int i = 0; i < 8; i++)
#pragma unroll
    for (int j = 0; j < 4; j++) acc[i][j] = f32x4{0.f, 0.f, 0.f, 0.f};

  const int NT = K >> 6;

#define STAGE_A(kh, kt, nb) do {                               \
    const u16* s_ = Ag + (size_t)(kt) * 64 + (kh) * 32;        \
    gll16(s_,         &lds[nb][0][kh][wid * 512]);             \
    gll16(s_ + rstep, &lds[nb][0][kh][4096 + wid * 512]);      \
  } while (0)
#define STAGE_B(kh, kt, nb) do {                               \
    const u16* s_ = Bg + (size_t)(kt) * 64 + (kh) * 32;        \
    gll16(s_,         &lds[nb][1][kh][wid * 512]);             \
    gll16(s_ + rstep, &lds[nb][1][kh][4096 + wid * 512]);      \
  } while (0)

  STAGE_A(0, 0, 0); STAGE_B(0, 0, 0);
  STAGE_A(1, 0, 0); STAGE_B(1, 0, 0);
  asm volatile("s_waitcnt vmcnt(4)" ::: "memory");
  BAR();

  for (int t = 0; t < NT; t++) {
    const int buf = t & 1, nb = buf ^ 1;
    const bool st = (t + 1 < NT);
    const u16* As0 = &lds[buf][0][0][0];
    const u16* As1 = &lds[buf][0][1][0];
    const u16* Bs0 = &lds[buf][1][0][0];
    const u16* Bs1 = &lds[buf][1][1][0];

    bf16x8 a[4], b[4];

    // ---- P0 ----
#pragma unroll
    for (int mi = 0; mi < 4; mi++)
      a[mi] = *(const bf16x8*)&As0[aoff + mi * 512];
#pragma unroll
    for (int nj = 0; nj < 4; nj++)
      b[nj] = *(const bf16x8*)&Bs0[boff + nj * 512];
    if (st) STAGE_A(0, t + 1, nb);
    BAR();
    __builtin_amdgcn_s_setprio(1);
#pragma unroll
    for (int mi = 0; mi < 4; mi++)
#pragma unroll
      for (int nj = 0; nj < 4; nj++)
        acc[mi][nj] = __builtin_amdgcn_mfma_f32_16x16x32_bf16(a[mi], b[nj], acc[mi][nj], 0, 0, 0);
    __builtin_amdgcn_s_setprio(0);
    BAR();

    // ---- P1 ----
#pragma unroll
    for (int mi = 0; mi < 4; mi++)
      a[mi] = *(const bf16x8*)&As0[aoff + (4 + mi) * 512];
    if (st) STAGE_B(0, t + 1, nb);
    BAR();
    __builtin_amdgcn_s_setprio(1);
#pragma unroll
    for (int mi = 0; mi < 4; mi++)
#pragma unroll
      for (int nj = 0; nj < 4; nj++)
        acc[4 + mi][nj] = __builtin_amdgcn_mfma_f32_16x16x32_bf16(a[mi], b[nj], acc[4 + mi][nj], 0, 0, 0);
    __builtin_amdgcn_s_setprio(0);
    if (t == NT - 1) asm volatile("s_waitcnt vmcnt(0)" ::: "memory");
    else             asm volatile("s_waitcnt vmcnt(4)" ::: "memory");
    BAR();

    // ---- P2 ----
#pragma unroll
    for (int mi = 0; mi < 4; mi++)
      a[mi] = *(const bf16x8*)&As1[aoff + mi * 512];
#pragma unroll
    for (int nj = 0; nj < 4; nj++)
      b[nj] = *(const bf16x8*)&Bs1[boff + nj * 512];
    if (st) STAGE_A(1, t + 1, nb);
    BAR();
    __builtin_amdgcn_s_setprio(1);
#pragma unroll
    for (int mi = 0; mi < 4; mi++)
#pragma unroll
      for (int nj = 0; nj < 4; nj++)
        acc[mi][nj] = __builtin_amdgcn_mfma_f32_16x16x32_bf16(a[mi], b[nj], acc[mi][nj], 0, 0, 0);
    __builtin_amdgcn_s_setprio(0);
    BAR();

    // ---- P3 ----
#pragma unroll
    for (int mi = 0; mi < 4; mi++)
      a[mi] = *(const bf16x8*)&As1[aoff + (4 + mi) * 512];
    if (st) STAGE_B(1, t + 1, nb);
    BAR();
    __builtin_amdgcn_s_setprio(1);
#pragma unroll
    for (int mi = 0; mi < 4; mi++)
#pragma unroll
      for (int nj = 0; nj < 4; nj++)
        acc[4 + mi][nj] = __builtin_amdgcn_mfma_f32_16x16x32_bf16(a[mi], b[nj], acc[4 + mi][nj], 0, 0, 0);
    __builtin_amdgcn_s_setprio(0);
    asm volatile("s_waitcnt vmcnt(4)" ::: "memory");
    BAR();
  }
#undef STAGE_A
#undef STAGE_B

  const int crow0 = mt * 256 + wr * 128 + kg * 4;
  const int ccol0 = nt * 256 + wc * 64 + fr;
#pragma unroll
  for (int nj = 0; nj < 4; nj++) {
    const int col = ccol0 + nj * 16;
    const float bb = bias[col];
#pragma unroll
    for (int mi = 0; mi < 8; mi++) {
      const int r0 = crow0 + mi * 16;
      f32x4 v = acc[mi][nj];
#pragma unroll
      for (int r = 0; r < 4; r++)
        C[(size_t)(r0 + r) * N + col] = f2bu(v[r] + bb);
    }
  }
}

// ---------- fused GEMM2 + bias + residual + LayerNorm ----------
// Block: 64 rows x full N=1024, 8 waves, wave tile 64x128 (acc 4x8 f32x4 =
// 128 VGPR/lane -> no spill). BK=32 single-buffered (A 4KB + B 64KB -> 2
// blocks/CU; cross-block overlap hides barrier drain, m97/m114). W_out is
// 2MB bf16 -> L2-resident per XCD. Epilogue: y = acc + out_b + slots;
// per-row LN via 16-lane shfl + cross-wave LDS reduce; fp32 final write.
__global__ __launch_bounds__(512, 2) void gemm2_ln_kernel(
    const u16* __restrict__ A,       // ctx bf16 [M][1024]
    const u16* __restrict__ Bw,      // W_out bf16 [1024][1024] (row = out col)
    const float* __restrict__ bias,  // out_b
    const float* __restrict__ slots, // [M][1024] f32
    const float* __restrict__ g, const float* __restrict__ lnb,
    float* __restrict__ out) {
  __shared__ u16 As[2048];            // [64][32]
  __shared__ u16 Bs[32768];           // [1024][32]
  __shared__ float red[8][64];        // per-wave row sums
  __shared__ float redq[8][64];       // per-wave row sumsq
  __shared__ float mu_s[64], rs_s[64];
  const int tid = threadIdx.x;
  const int lane = tid & 63, wid = tid >> 6;
  const int fr = lane & 15, kg = lane >> 4;
  const int K = 1024;

  // XCD swizzle: grid 1536 = 8 * 192 (bijective)
  const int bid = blockIdx.x;
  const int mt = (bid & 7) * 192 + (bid >> 3);
  const int brow = mt * 64;

  // staging (pre-swizzled source col8, same involution as gemm256)
  const int scol = (tid & 3) ^ ((tid >> 3) & 3);
  const u16* Ag = A + (size_t)(brow + ((tid & 255) >> 2)) * K + scol * 8;  // t<256
  const u16* Bg = Bw + (size_t)(tid >> 2) * K + scol * 8;                 // +j*128 rows

  // fragment read offsets (u16), swizzled on the read side
  const int sw = (fr >> 1) & 3;
  const int kgs = (kg ^ sw) * 8;
  const int aoff = fr * 32 + kgs;                   // + mi*512 (16 rows)
  const int boff = (wid * 128 + fr) * 32 + kgs;     // + nj*512

  f32x4 acc[4][8];
#pragma unroll
  for (int i = 0; i < 4; i++)
#pragma unroll
    for (int j = 0; j < 8; j++) acc[i][j] = f32x4{0.f, 0.f, 0.f, 0.f};

  for (int kt = 0; kt < 32; kt++) {
    if (tid < 256) gll16(Ag + kt * 32, &As[wid * 512]);   // waves 0-3 stage A
#pragma unroll
    for (int j = 0; j < 8; j++)
      gll16(Bg + (size_t)j * 128 * K + kt * 32, &Bs[j * 4096 + wid * 512]);
    __syncthreads();   // drain vmcnt -> tile visible

    bf16x8 af[4], bf[8];
#pragma unroll
    for (int mi = 0; mi < 4; mi++)
      af[mi] = *(const bf16x8*)&As[aoff + mi * 512];
#pragma unroll
    for (int nj = 0; nj < 8; nj++)
      bf[nj] = *(const bf16x8*)&Bs[boff + nj * 512];
    __builtin_amdgcn_s_setprio(1);
#pragma unroll
    for (int mi = 0; mi < 4; mi++)
#pragma unroll
      for (int nj = 0; nj < 8; nj++)
        acc[mi][nj] = __builtin_amdgcn_mfma_f32_16x16x32_bf16(
            af[mi], bf[nj], acc[mi][nj], 0, 0, 0);
    __builtin_amdgcn_s_setprio(0);
    __syncthreads();   // reads done before next overwrite
  }

  // ---- epilogue: bias + residual, per-row LN, final fp32 write ----
  float bb[8], gg[8], lb[8];
#pragma unroll
  for (int nj = 0; nj < 8; nj++) {
    const int col = wid * 128 + nj * 16 + fr;
    bb[nj] = bias[col]; gg[nj] = g[col]; lb[nj] = lnb[col];
  }

#pragma unroll
  for (int mi = 0; mi < 4; mi++)
#pragma unroll
    for (int r = 0; r < 4; r++) {
      const int rl = mi * 16 + kg * 4 + r;                 // local row 0..63
      const size_t gr = (size_t)(brow + rl) * 1024;
      float s = 0.f, q = 0.f;
#pragma unroll
      for (int nj = 0; nj < 8; nj++) {
        const int col = wid * 128 + nj * 16 + fr;
        float y = acc[mi][nj][r] + bb[nj] + slots[gr + col];
        acc[mi][nj][r] = y;
        s += y; q += y * y;
      }
#pragma unroll
      for (int m = 1; m < 16; m <<= 1) {   // reduce over the 16 fr-lanes
        s += __shfl_xor(s, m);
        q += __shfl_xor(q, m);
      }
      if (fr == 0) { red[wid][rl] = s; redq[wid][rl] = q; }
    }
  __syncthreads();

  if (tid < 64) {
    float s = 0.f, q = 0.f;
#pragma unroll
    for (int w = 0; w < 8; w++) { s += red[w][tid]; q += redq[w][tid]; }
    const float mu = s * (1.0f / 1024.0f);
    const float var = q * (1.0f / 1024.0f) - mu * mu;
    mu_s[tid] = mu;
    rs_s[tid] = rsqrtf(var + 1e-5f);
  }
  __syncthreads();

#pragma unroll
  for (int mi = 0; mi < 4; mi++)
#pragma unroll
    for (int r = 0; r < 4; r++) {
      const int rl = mi * 16 + kg * 4 + r;
      const float mu = mu_s[rl], rs = rs_s[rl];
      const size_t gr = (size_t)(brow + rl) * 1024;
#pragma unroll
      for (int nj = 0; nj < 8; nj++) {
        const int col = wid * 128 + nj * 16 + fr;
        out[gr + col] = (acc[mi][nj][r] - mu) * rs * gg[nj] + lb[nj];
      }
    }
}

// ---------- tiny attention: S=3, 16 heads of d=64 (grid-stride) ----------
__global__ __launch_bounds__(256) void attn3_kernel(
    const u16* __restrict__ qkv, u16* __restrict__ ctx) {
  const int tid = threadIdx.x;
  const int lane = tid & 63, wid = tid >> 6;
  const int nunit = 32768 * 4;
  for (int unit = blockIdx.x * 4 + wid; unit < nunit; unit += gridDim.x * 4) {
    const int b = unit >> 2, hg = unit & 3;
    const size_t qbase = (size_t)b * 3 * 3072 + hg * 256 + lane * 4;

    float q[3][4], k[3][4], v[3][4];
#pragma unroll
    for (int s = 0; s < 3; s++) {
      ushort4 uq = *(const ushort4*)(qkv + qbase + (size_t)s * 3072);
      ushort4 uk = *(const ushort4*)(qkv + qbase + (size_t)s * 3072 + 1024);
      ushort4 uv = *(const ushort4*)(qkv + qbase + (size_t)s * 3072 + 2048);
      q[s][0] = b2f(uq.x); q[s][1] = b2f(uq.y); q[s][2] = b2f(uq.z); q[s][3] = b2f(uq.w);
      k[s][0] = b2f(uk.x); k[s][1] = b2f(uk.y); k[s][2] = b2f(uk.z); k[s][3] = b2f(uk.w);
      v[s][0] = b2f(uv.x); v[s][1] = b2f(uv.y); v[s][2] = b2f(uv.z); v[s][3] = b2f(uv.w);
    }

    float sc[3][3];
#pragma unroll
    for (int i = 0; i < 3; i++)
#pragma unroll
      for (int j = 0; j < 3; j++) {
        float p = q[i][0] * k[j][0] + q[i][1] * k[j][1] +
                  q[i][2] * k[j][2] + q[i][3] * k[j][3];
        p += __shfl_xor(p, 1);
        p += __shfl_xor(p, 2);
        p += __shfl_xor(p, 4);
        p += __shfl_xor(p, 8);   // 16-lane group = one head's 64 dims
        sc[i][j] = p;
      }

    float o[3][4];
#pragma unroll
    for (int i = 0; i < 3; i++) {
      float mx = fmaxf(sc[i][0], fmaxf(sc[i][1], sc[i][2]));
      float e0 = __expf((sc[i][0] - mx) * 0.125f);
      float e1 = __expf((sc[i][1] - mx) * 0.125f);
      float e2 = __expf((sc[i][2] - mx) * 0.125f);
      float inv = 1.f / (e0 + e1 + e2);
      e0 *= inv; e1 *= inv; e2 *= inv;
#pragma unroll
      for (int d = 0; d < 4; d++)
        o[i][d] = e0 * v[0][d] + e1 * v[1][d] + e2 * v[2][d];
    }

    const size_t obase = (size_t)b * 3 * 1024 + hg * 256 + lane * 4;
#pragma unroll
    for (int i = 0; i < 3; i++) {
      ushort4 ov;
      ov.x = f2bu(o[i][0]); ov.y = f2bu(o[i][1]);
      ov.z = f2bu(o[i][2]); ov.w = f2bu(o[i][3]);
      *(ushort4*)(ctx + obase + (size_t)i * 1024) = ov;
    }
  }
}

extern "C" void kernel_launch(void* const* d_in, const int* in_sizes, int n_in,
                              void* d_out, int out_size, void* d_ws, size_t ws_size,
                              hipStream_t stream) {
  const float* slots = (const float*)d_in[0];
  const float* in_w  = (const float*)d_in[1];
  const float* in_b  = (const float*)d_in[2];
  const float* out_w = (const float*)d_in[3];
  const float* out_b = (const float*)d_in[4];
  const float* ln_g  = (const float*)d_in[5];
  const float* ln_b  = (const float*)d_in[6];
  float* out = (float*)d_out;

  const int M = 32768 * 3;  // 98304 rows

  // workspace layout:
  //   Abf   [M*1024 bf16] = 201,326,592 B   (later reused as ctx)
  //   Winb  [3072*1024]   =   6,291,456 B
  //   Woutb [1024*1024]   =   2,097,152 B
  //   qkv   [M*3072]      = 603,979,776 B
  char* ws = (char*)d_ws;
  u16* Abf   = (u16*)ws;
  u16* Winb  = (u16*)(ws + 201326592);
  u16* Woutb = (u16*)(ws + 207618048);
  u16* qkv   = (u16*)(ws + 209715200);

  cvt_f32_bf16_kernel<<<2048, 256, 0, stream>>>(slots, Abf, M * 1024 / 4);
  cvt_f32_bf16_kernel<<<2048, 256, 0, stream>>>(in_w, Winb, 3072 * 1024 / 4);
  cvt_f32_bf16_kernel<<<1024, 256, 0, stream>>>(out_w, Woutb, 1024 * 1024 / 4);

  // qkv = Abf @ Winb^T + in_b : M x 3072, tiles 384 x 12
  gemm256_bt_bias<<<384 * 12, 512, 0, stream>>>(Abf, Winb, in_b, qkv, 3072, 1024, 12);

  // ctx (overwrites Abf)
  attn3_kernel<<<2048, 256, 0, stream>>>(qkv, Abf);

  // out = LN(slots + ctx @ Woutb^T + out_b) * g + b   (fused, fp32 out)
  gemm2_ln_kernel<<<1536, 512, 0, stream>>>(Abf, Woutb, out_b, slots, ln_g, ln_b, out);
}

// Round 9
// 1428.898 us; speedup vs baseline: 1.0077x; 1.0077x over previous
//
#include <hip/hip_runtime.h>
#include <stdint.h>

typedef unsigned short u16;
typedef float f32x4 __attribute__((ext_vector_type(4)));
typedef short bf16x8 __attribute__((ext_vector_type(8)));

// ---------- helpers ----------
__device__ __forceinline__ u16 f2bu(float f) {           // fp32 -> bf16 (RNE)
  uint32_t x = __builtin_bit_cast(uint32_t, f);
  x += 0x7fffu + ((x >> 16) & 1u);
  return (u16)(x >> 16);
}
__device__ __forceinline__ float b2f(u16 u) {            // bf16 -> fp32 (exact)
  return __builtin_bit_cast(float, (uint32_t)u << 16);
}
__device__ __forceinline__ void gll16(const void* g, void* l) {
  __builtin_amdgcn_global_load_lds(
      (const __attribute__((address_space(1))) void*)g,
      (__attribute__((address_space(3))) void*)l, 16, 0, 0);
}

// ---------- fp32 -> bf16 convert ----------
__global__ __launch_bounds__(256) void cvt_f32_bf16_kernel(
    const float* __restrict__ in, u16* __restrict__ out, int n4) {
  int i = blockIdx.x * 256 + threadIdx.x;
  const int stride = gridDim.x * 256;
  for (; i < n4; i += stride) {
    float4 f = reinterpret_cast<const float4*>(in)[i];
    ushort4 o;
    o.x = f2bu(f.x); o.y = f2bu(f.y); o.z = f2bu(f.z); o.w = f2bu(f.w);
    reinterpret_cast<ushort4*>(out)[i] = o;
  }
}

// ---------- 256x256 GEMM, BK=32, double-buffered, 64KB LDS -> 2 blocks/CU ----
// C[m,n] = sum_k A[m,k]*B[n,k] + bias[n], bf16 in/out, fp32 accum.
// m97 structure: one __syncthreads per K-tile (implicit vmcnt(0)+lgkm drain
// certifies staged tile landed AND all LDS reads done). The co-resident block
// on the CU hides the drain (m114 wave-level MFMA/VMEM overlap). Coalesced
// 16B staging slots; swizzle involution applied to BOTH gll source and
// ds_read address (proven 0-conflict in r3-r8).
__global__ __launch_bounds__(512, 2) void gemm256_bt_bias(
    const u16* __restrict__ A, const u16* __restrict__ Bw,
    const float* __restrict__ bias, u16* __restrict__ C,
    int N, int K, int ntn) {
  __shared__ u16 lds[2][2][8192];   // [buf][A=0/B=1][256 rows * 32 cols] = 64KB
  const int tid = threadIdx.x;
  const int lane = tid & 63, wid = tid >> 6;
  const int wr = wid >> 2, wc = wid & 3;        // wave grid 2 (M) x 4 (N)
  const int fr = lane & 15, kg = lane >> 4;

  // XCD-aware swizzle (grid % 8 == 0 for both calls)
  const int cpx = (int)gridDim.x >> 3;
  const int bid = blockIdx.x;
  const int sid = (bid & 7) * cpx + (bid >> 3);
  const int mt = sid / ntn, nt = sid % ntn;

  // staging: flat slot s = tid (+512 for 2nd round); row = s>>2, col8 = s&3.
  // source col8 pre-swizzled: col8' = col8 ^ ((row>>1)&3)
  const int srow = tid >> 2;                    // 0..127 (round 1 adds 128)
  const int scol = (tid & 3) ^ ((tid >> 3) & 3);
  const u16* Ag = A + (size_t)(mt * 256 + srow) * K + scol * 8;
  const u16* Bg = Bw + (size_t)(nt * 256 + srow) * K + scol * 8;
  const size_t rstep = (size_t)128 * K;

  // fragment read offsets (u16), same involution on the read side
  const int sw = (fr >> 1) & 3;
  const int kgs = (kg ^ sw) * 8;
  const int aoff = (wr * 128 + fr) * 32 + kgs;
  const int boff = (wc * 64 + fr) * 32 + kgs;

  f32x4 acc[8][4];
#pragma unroll
  for (int i = 0; i < 8; i++)
#pragma unroll
    for (int j = 0; j < 4; j++) acc[i][j] = f32x4{0.f, 0.f, 0.f, 0.f};

  const int NT = K >> 5;

#define STAGE(b, kt) do {                                   \
    const u16* a_ = Ag + (size_t)(kt) * 32;                 \
    const u16* b_ = Bg + (size_t)(kt) * 32;                 \
    gll16(a_,         &lds[(b)][0][wid * 512]);             \
    gll16(a_ + rstep, &lds[(b)][0][4096 + wid * 512]);      \
    gll16(b_,         &lds[(b)][1][wid * 512]);             \
    gll16(b_ + rstep, &lds[(b)][1][4096 + wid * 512]);      \
  } while (0)

  STAGE(0, 0);
  __syncthreads();              // tile 0 landed (vmcnt(0) drain)

  for (int t = 0; t < NT; t++) {
    const int cur = t & 1;
    if (t + 1 < NT) STAGE(cur ^ 1, t + 1);   // prefetch next tile
    const u16* As = &lds[cur][0][0];
    const u16* Bs = &lds[cur][1][0];
    bf16x8 a[8], b[4];
#pragma unroll
    for (int mi = 0; mi < 8; mi++)
      a[mi] = *(const bf16x8*)&As[aoff + mi * 512];
#pragma unroll
    for (int nj = 0; nj < 4; nj++)
      b[nj] = *(const bf16x8*)&Bs[boff + nj * 512];
    __builtin_amdgcn_s_setprio(1);
#pragma unroll
    for (int mi = 0; mi < 8; mi++)
#pragma unroll
      for (int nj = 0; nj < 4; nj++)
        acc[mi][nj] = __builtin_amdgcn_mfma_f32_16x16x32_bf16(
            a[mi], b[nj], acc[mi][nj], 0, 0, 0);
    __builtin_amdgcn_s_setprio(0);
    __syncthreads();   // next tile landed + this tile's reads done (WAR safe)
  }
#undef STAGE

  // C/D layout per 16x16 frag: col = lane&15, row = (lane>>4)*4 + reg
  const int crow0 = mt * 256 + wr * 128 + kg * 4;
  const int ccol0 = nt * 256 + wc * 64 + fr;
#pragma unroll
  for (int nj = 0; nj < 4; nj++) {
    const int col = ccol0 + nj * 16;
    const float bb = bias[col];
#pragma unroll
    for (int mi = 0; mi < 8; mi++) {
      const int r0 = crow0 + mi * 16;
      f32x4 v = acc[mi][nj];
#pragma unroll
      for (int r = 0; r < 4; r++)
        C[(size_t)(r0 + r) * N + col] = f2bu(v[r] + bb);
    }
  }
}

// ---------- tiny attention: S=3, 16 heads of d=64 (grid-stride) ----------
__global__ __launch_bounds__(256) void attn3_kernel(
    const u16* __restrict__ qkv, u16* __restrict__ ctx) {
  const int tid = threadIdx.x;
  const int lane = tid & 63, wid = tid >> 6;
  const int nunit = 32768 * 4;
  for (int unit = blockIdx.x * 4 + wid; unit < nunit; unit += gridDim.x * 4) {
    const int b = unit >> 2, hg = unit & 3;
    const size_t qbase = (size_t)b * 3 * 3072 + hg * 256 + lane * 4;

    float q[3][4], k[3][4], v[3][4];
#pragma unroll
    for (int s = 0; s < 3; s++) {
      ushort4 uq = *(const ushort4*)(qkv + qbase + (size_t)s * 3072);
      ushort4 uk = *(const ushort4*)(qkv + qbase + (size_t)s * 3072 + 1024);
      ushort4 uv = *(const ushort4*)(qkv + qbase + (size_t)s * 3072 + 2048);
      q[s][0] = b2f(uq.x); q[s][1] = b2f(uq.y); q[s][2] = b2f(uq.z); q[s][3] = b2f(uq.w);
      k[s][0] = b2f(uk.x); k[s][1] = b2f(uk.y); k[s][2] = b2f(uk.z); k[s][3] = b2f(uk.w);
      v[s][0] = b2f(uv.x); v[s][1] = b2f(uv.y); v[s][2] = b2f(uv.z); v[s][3] = b2f(uv.w);
    }

    float sc[3][3];
#pragma unroll
    for (int i = 0; i < 3; i++)
#pragma unroll
      for (int j = 0; j < 3; j++) {
        float p = q[i][0] * k[j][0] + q[i][1] * k[j][1] +
                  q[i][2] * k[j][2] + q[i][3] * k[j][3];
        p += __shfl_xor(p, 1);
        p += __shfl_xor(p, 2);
        p += __shfl_xor(p, 4);
        p += __shfl_xor(p, 8);   // 16-lane group = one head's 64 dims
        sc[i][j] = p;
      }

    float o[3][4];
#pragma unroll
    for (int i = 0; i < 3; i++) {
      float mx = fmaxf(sc[i][0], fmaxf(sc[i][1], sc[i][2]));
      float e0 = __expf((sc[i][0] - mx) * 0.125f);
      float e1 = __expf((sc[i][1] - mx) * 0.125f);
      float e2 = __expf((sc[i][2] - mx) * 0.125f);
      float inv = 1.f / (e0 + e1 + e2);
      e0 *= inv; e1 *= inv; e2 *= inv;
#pragma unroll
      for (int d = 0; d < 4; d++)
        o[i][d] = e0 * v[0][d] + e1 * v[1][d] + e2 * v[2][d];
    }

    const size_t obase = (size_t)b * 3 * 1024 + hg * 256 + lane * 4;
#pragma unroll
    for (int i = 0; i < 3; i++) {
      ushort4 ov;
      ov.x = f2bu(o[i][0]); ov.y = f2bu(o[i][1]);
      ov.z = f2bu(o[i][2]); ov.w = f2bu(o[i][3]);
      *(ushort4*)(ctx + obase + (size_t)i * 1024) = ov;
    }
  }
}

// ---------- residual + LayerNorm: wave per row of 1024 ----------
__global__ __launch_bounds__(256) void ln_kernel(
    const float* __restrict__ slots, const u16* __restrict__ ao,
    const float* __restrict__ g, const float* __restrict__ bvec,
    float* __restrict__ out) {
  const int tid = threadIdx.x;
  const int lane = tid & 63, wid = tid >> 6;
  const int row = blockIdx.x * 4 + wid;
  const size_t rb = (size_t)row * 1024;

  float y[16];
  float sum = 0.f, sq = 0.f;
#pragma unroll
  for (int c = 0; c < 4; c++) {
    const int col = c * 256 + lane * 4;
    float4 sl = *(const float4*)(slots + rb + col);
    ushort4 a4 = *(const ushort4*)(ao + rb + col);
    float y0 = sl.x + b2f(a4.x), y1 = sl.y + b2f(a4.y);
    float y2 = sl.z + b2f(a4.z), y3 = sl.w + b2f(a4.w);
    y[c * 4 + 0] = y0; y[c * 4 + 1] = y1; y[c * 4 + 2] = y2; y[c * 4 + 3] = y3;
    sum += y0 + y1 + y2 + y3;
    sq += y0 * y0 + y1 * y1 + y2 * y2 + y3 * y3;
  }
#pragma unroll
  for (int m = 1; m < 64; m <<= 1) {
    sum += __shfl_xor(sum, m);
    sq  += __shfl_xor(sq, m);
  }
  const float mu = sum * (1.0f / 1024.0f);
  const float var = sq * (1.0f / 1024.0f) - mu * mu;
  const float rs = rsqrtf(var + 1e-5f);
#pragma unroll
  for (int c = 0; c < 4; c++) {
    const int col = c * 256 + lane * 4;
    float4 gg = *(const float4*)(g + col);
    float4 bb = *(const float4*)(bvec + col);
    float4 ov;
    ov.x = (y[c * 4 + 0] - mu) * rs * gg.x + bb.x;
    ov.y = (y[c * 4 + 1] - mu) * rs * gg.y + bb.y;
    ov.z = (y[c * 4 + 2] - mu) * rs * gg.z + bb.z;
    ov.w = (y[c * 4 + 3] - mu) * rs * gg.w + bb.w;
    *(float4*)(out + rb + col) = ov;
  }
}

extern "C" void kernel_launch(void* const* d_in, const int* in_sizes, int n_in,
                              void* d_out, int out_size, void* d_ws, size_t ws_size,
                              hipStream_t stream) {
  const float* slots = (const float*)d_in[0];
  const float* in_w  = (const float*)d_in[1];
  const float* in_b  = (const float*)d_in[2];
  const float* out_w = (const float*)d_in[3];
  const float* out_b = (const float*)d_in[4];
  const float* ln_g  = (const float*)d_in[5];
  const float* ln_b  = (const float*)d_in[6];
  float* out = (float*)d_out;

  const int M = 32768 * 3;  // 98304 rows

  // workspace layout (aliased):
  //   Abf   [M*1024 bf16] = 201,326,592 B   (later reused as ctx)
  //   Winb  [3072*1024]   =   6,291,456 B
  //   Woutb [1024*1024]   =   2,097,152 B
  //   qkv   [M*3072]      = 603,979,776 B   (first third later reused as attn_out)
  char* ws = (char*)d_ws;
  u16* Abf   = (u16*)ws;
  u16* Winb  = (u16*)(ws + 201326592);
  u16* Woutb = (u16*)(ws + 207618048);
  u16* qkv   = (u16*)(ws + 209715200);

  cvt_f32_bf16_kernel<<<2048, 256, 0, stream>>>(slots, Abf, M * 1024 / 4);
  cvt_f32_bf16_kernel<<<2048, 256, 0, stream>>>(in_w, Winb, 3072 * 1024 / 4);
  cvt_f32_bf16_kernel<<<1024, 256, 0, stream>>>(out_w, Woutb, 1024 * 1024 / 4);

  // qkv = Abf @ Winb^T + in_b : M x 3072, tiles 384 x 12
  gemm256_bt_bias<<<384 * 12, 512, 0, stream>>>(Abf, Winb, in_b, qkv, 3072, 1024, 12);

  // ctx (overwrites Abf)
  attn3_kernel<<<2048, 256, 0, stream>>>(qkv, Abf);

  // attn_out = ctx @ Woutb^T + out_b (overwrites start of qkv) : M x 1024, tiles 384 x 4
  gemm256_bt_bias<<<384 * 4, 512, 0, stream>>>(Abf, Woutb, out_b, qkv, 1024, 1024, 4);

  // out = LN(slots + attn_out) * g + b
  ln_kernel<<<M / 4, 256, 0, stream>>>(slots, qkv, ln_g, ln_b, out);
}

// Round 10
// 1406.507 us; speedup vs baseline: 1.0237x; 1.0159x over previous
//
#include <hip/hip_runtime.h>
#include <stdint.h>

typedef unsigned short u16;
typedef float f32x4 __attribute__((ext_vector_type(4)));
typedef short bf16x8 __attribute__((ext_vector_type(8)));

// ---------- helpers ----------
__device__ __forceinline__ u16 f2bu(float f) {           // fp32 -> bf16 (RNE)
  uint32_t x = __builtin_bit_cast(uint32_t, f);
  x += 0x7fffu + ((x >> 16) & 1u);
  return (u16)(x >> 16);
}
__device__ __forceinline__ float b2f(u16 u) {            // bf16 -> fp32 (exact)
  return __builtin_bit_cast(float, (uint32_t)u << 16);
}
__device__ __forceinline__ void gll16(const void* g, void* l) {
  __builtin_amdgcn_global_load_lds(
      (const __attribute__((address_space(1))) void*)g,
      (__attribute__((address_space(3))) void*)l, 16, 0, 0);
}

// ---------- fp32 -> bf16 convert ----------
__global__ __launch_bounds__(256) void cvt_f32_bf16_kernel(
    const float* __restrict__ in, u16* __restrict__ out, int n4) {
  int i = blockIdx.x * 256 + threadIdx.x;
  const int stride = gridDim.x * 256;
  for (; i < n4; i += stride) {
    float4 f = reinterpret_cast<const float4*>(in)[i];
    ushort4 o;
    o.x = f2bu(f.x); o.y = f2bu(f.y); o.z = f2bu(f.z); o.w = f2bu(f.w);
    reinterpret_cast<ushort4*>(out)[i] = o;
  }
}

// ---------- 256x256 GEMM, 16 waves (1024 thr), wave-tile 64x64 ----------
// C[m,n] = sum_k A[m,k]*B[n,k] + bias[n], bf16 in/out, fp32 accum.
// Key change vs r9: acc = 64 regs/lane (not 128) -> total ~120 VGPR -> 4
// waves/SIMD co-resident (vs 2). Between barriers the SIMD interleaves one
// wave's ds_reads with another's MFMAs (m114 overlap) -- the lever all the
// barrier-locked 8-wave schedules lacked. BK=32 double-buffer, one
// __syncthreads per K-tile (drains vmcnt for staged tile + lgkm for WAR).
// Staging: 1 gll/thread/matrix, coalesced 16B slots; swizzle involution
// col8' = col8 ^ ((row>>1)&3) on BOTH gll source and ds_read (0-conflict,
// proven r3-r9). lda for strided A (qkv k-slice), ldc for strided C.
__global__ __launch_bounds__(1024, 4) void gemm256_bt_bias(
    const u16* __restrict__ A, const u16* __restrict__ Bw,
    const float* __restrict__ bias, u16* __restrict__ C,
    int N, int K, int lda, int ldc, int ntn) {
  __shared__ u16 lds[2][2][8192];   // [buf][A=0/B=1][256 rows * 32 cols] = 64KB
  const int tid = threadIdx.x;
  const int lane = tid & 63, wid = tid >> 6;   // wid 0..15
  const int wr = wid >> 2, wc = wid & 3;        // wave grid 4 (M) x 4 (N)
  const int fr = lane & 15, kg = lane >> 4;

  // XCD-aware swizzle (grid % 8 == 0 for both calls)
  const int cpx = (int)gridDim.x >> 3;
  const int bid = blockIdx.x;
  const int sid = (bid & 7) * cpx + (bid >> 3);
  const int mt = sid / ntn, nt = sid % ntn;

  // staging: slot s = tid; row = s>>2 (0..255), col8 = s&3.
  // source col8 pre-swizzled: col8' = col8 ^ ((row>>1)&3)
  const int srow = tid >> 2;
  const int scol = (tid & 3) ^ ((tid >> 3) & 3);
  const u16* Ag = A + (size_t)(mt * 256 + srow) * lda + scol * 8;
  const u16* Bg = Bw + (size_t)(nt * 256 + srow) * K + scol * 8;

  // fragment read offsets (u16), same involution on the read side
  const int sw = (fr >> 1) & 3;
  const int kgs = (kg ^ sw) * 8;
  const int aoff = (wr * 64 + fr) * 32 + kgs;
  const int boff = (wc * 64 + fr) * 32 + kgs;

  f32x4 acc[4][4];
#pragma unroll
  for (int i = 0; i < 4; i++)
#pragma unroll
    for (int j = 0; j < 4; j++) acc[i][j] = f32x4{0.f, 0.f, 0.f, 0.f};

  const int NT = K >> 5;

#define STAGE(b, kt) do {                                   \
    gll16(Ag + (size_t)(kt) * 32, &lds[(b)][0][wid * 512]); \
    gll16(Bg + (size_t)(kt) * 32, &lds[(b)][1][wid * 512]); \
  } while (0)

  STAGE(0, 0);
  __syncthreads();              // tile 0 landed (vmcnt(0) drain)

  for (int t = 0; t < NT; t++) {
    const int cur = t & 1;
    if (t + 1 < NT) STAGE(cur ^ 1, t + 1);   // prefetch next tile
    const u16* As = &lds[cur][0][0];
    const u16* Bs = &lds[cur][1][0];
    bf16x8 a[4], b[4];
#pragma unroll
    for (int nj = 0; nj < 4; nj++)
      b[nj] = *(const bf16x8*)&Bs[boff + nj * 512];
#pragma unroll
    for (int mi = 0; mi < 4; mi++)
      a[mi] = *(const bf16x8*)&As[aoff + mi * 512];
    __builtin_amdgcn_s_setprio(1);
#pragma unroll
    for (int mi = 0; mi < 4; mi++)
#pragma unroll
      for (int nj = 0; nj < 4; nj++)
        acc[mi][nj] = __builtin_amdgcn_mfma_f32_16x16x32_bf16(
            a[mi], b[nj], acc[mi][nj], 0, 0, 0);
    __builtin_amdgcn_s_setprio(0);
    __syncthreads();   // next tile landed + this tile's reads done (WAR safe)
  }
#undef STAGE

  // C/D layout per 16x16 frag: col = lane&15, row = (lane>>4)*4 + reg
  const int crow0 = mt * 256 + wr * 64 + kg * 4;
  const int ccol0 = nt * 256 + wc * 64 + fr;
#pragma unroll
  for (int nj = 0; nj < 4; nj++) {
    const int col = ccol0 + nj * 16;
    const float bb = bias[col];
#pragma unroll
    for (int mi = 0; mi < 4; mi++) {
      const int r0 = crow0 + mi * 16;
      f32x4 v = acc[mi][nj];
#pragma unroll
      for (int r = 0; r < 4; r++)
        C[(size_t)(r0 + r) * ldc + col] = f2bu(v[r] + bb);
    }
  }
}

// ---------- tiny attention: S=3, 16 heads of d=64 (grid-stride) ----------
// Writes ctx IN-PLACE into the k-slice (cols 1024..2047) of qkv: each unit
// loads its own q,k,v into registers first, then stores; units own disjoint
// (rows, col-window) so no cross-thread aliasing.
__global__ __launch_bounds__(256) void attn3_kernel(
    u16* __restrict__ qkv) {
  const int tid = threadIdx.x;
  const int lane = tid & 63, wid = tid >> 6;
  const int nunit = 32768 * 4;
  for (int unit = blockIdx.x * 4 + wid; unit < nunit; unit += gridDim.x * 4) {
    const int b = unit >> 2, hg = unit & 3;
    const size_t qbase = (size_t)b * 3 * 3072 + hg * 256 + lane * 4;

    float q[3][4], k[3][4], v[3][4];
#pragma unroll
    for (int s = 0; s < 3; s++) {
      ushort4 uq = *(const ushort4*)(qkv + qbase + (size_t)s * 3072);
      ushort4 uk = *(const ushort4*)(qkv + qbase + (size_t)s * 3072 + 1024);
      ushort4 uv = *(const ushort4*)(qkv + qbase + (size_t)s * 3072 + 2048);
      q[s][0] = b2f(uq.x); q[s][1] = b2f(uq.y); q[s][2] = b2f(uq.z); q[s][3] = b2f(uq.w);
      k[s][0] = b2f(uk.x); k[s][1] = b2f(uk.y); k[s][2] = b2f(uk.z); k[s][3] = b2f(uk.w);
      v[s][0] = b2f(uv.x); v[s][1] = b2f(uv.y); v[s][2] = b2f(uv.z); v[s][3] = b2f(uv.w);
    }

    float sc[3][3];
#pragma unroll
    for (int i = 0; i < 3; i++)
#pragma unroll
      for (int j = 0; j < 3; j++) {
        float p = q[i][0] * k[j][0] + q[i][1] * k[j][1] +
                  q[i][2] * k[j][2] + q[i][3] * k[j][3];
        p += __shfl_xor(p, 1);
        p += __shfl_xor(p, 2);
        p += __shfl_xor(p, 4);
        p += __shfl_xor(p, 8);   // 16-lane group = one head's 64 dims
        sc[i][j] = p;
      }

    float o[3][4];
#pragma unroll
    for (int i = 0; i < 3; i++) {
      float mx = fmaxf(sc[i][0], fmaxf(sc[i][1], sc[i][2]));
      float e0 = __expf((sc[i][0] - mx) * 0.125f);
      float e1 = __expf((sc[i][1] - mx) * 0.125f);
      float e2 = __expf((sc[i][2] - mx) * 0.125f);
      float inv = 1.f / (e0 + e1 + e2);
      e0 *= inv; e1 *= inv; e2 *= inv;
#pragma unroll
      for (int d = 0; d < 4; d++)
        o[i][d] = e0 * v[0][d] + e1 * v[1][d] + e2 * v[2][d];
    }

    // write ctx into the k-slice of the same rows
#pragma unroll
    for (int i = 0; i < 3; i++) {
      ushort4 ov;
      ov.x = f2bu(o[i][0]); ov.y = f2bu(o[i][1]);
      ov.z = f2bu(o[i][2]); ov.w = f2bu(o[i][3]);
      *(ushort4*)(qkv + qbase + (size_t)i * 3072 + 1024) = ov;
    }
  }
}

// ---------- residual + LayerNorm: wave per row of 1024 ----------
// slots read as bf16 (Abf copy, halves residual read traffic); attn_out read
// strided from the q-slice of qkv (ldao = 3072).
__global__ __launch_bounds__(256) void ln_kernel(
    const u16* __restrict__ slots_bf, const u16* __restrict__ ao,
    const float* __restrict__ g, const float* __restrict__ bvec,
    float* __restrict__ out) {
  const int tid = threadIdx.x;
  const int lane = tid & 63, wid = tid >> 6;
  const int row = blockIdx.x * 4 + wid;
  const size_t rb = (size_t)row * 1024;
  const size_t ab = (size_t)row * 3072;

  float y[16];
  float sum = 0.f, sq = 0.f;
#pragma unroll
  for (int c = 0; c < 4; c++) {
    const int col = c * 256 + lane * 4;
    ushort4 s4 = *(const ushort4*)(slots_bf + rb + col);
    ushort4 a4 = *(const ushort4*)(ao + ab + col);
    float y0 = b2f(s4.x) + b2f(a4.x), y1 = b2f(s4.y) + b2f(a4.y);
    float y2 = b2f(s4.z) + b2f(a4.z), y3 = b2f(s4.w) + b2f(a4.w);
    y[c * 4 + 0] = y0; y[c * 4 + 1] = y1; y[c * 4 + 2] = y2; y[c * 4 + 3] = y3;
    sum += y0 + y1 + y2 + y3;
    sq += y0 * y0 + y1 * y1 + y2 * y2 + y3 * y3;
  }
#pragma unroll
  for (int m = 1; m < 64; m <<= 1) {
    sum += __shfl_xor(sum, m);
    sq  += __shfl_xor(sq, m);
  }
  const float mu = sum * (1.0f / 1024.0f);
  const float var = sq * (1.0f / 1024.0f) - mu * mu;
  const float rs = rsqrtf(var + 1e-5f);
#pragma unroll
  for (int c = 0; c < 4; c++) {
    const int col = c * 256 + lane * 4;
    float4 gg = *(const float4*)(g + col);
    float4 bb = *(const float4*)(bvec + col);
    float4 ov;
    ov.x = (y[c * 4 + 0] - mu) * rs * gg.x + bb.x;
    ov.y = (y[c * 4 + 1] - mu) * rs * gg.y + bb.y;
    ov.z = (y[c * 4 + 2] - mu) * rs * gg.z + bb.z;
    ov.w = (y[c * 4 + 3] - mu) * rs * gg.w + bb.w;
    *(float4*)(out + rb + col) = ov;
  }
}

extern "C" void kernel_launch(void* const* d_in, const int* in_sizes, int n_in,
                              void* d_out, int out_size, void* d_ws, size_t ws_size,
                              hipStream_t stream) {
  const float* slots = (const float*)d_in[0];
  const float* in_w  = (const float*)d_in[1];
  const float* in_b  = (const float*)d_in[2];
  const float* out_w = (const float*)d_in[3];
  const float* out_b = (const float*)d_in[4];
  const float* ln_g  = (const float*)d_in[5];
  const float* ln_b  = (const float*)d_in[6];
  float* out = (float*)d_out;

  const int M = 32768 * 3;  // 98304 rows

  // workspace layout:
  //   Abf   [M*1024 bf16] = 201,326,592 B   (stays live: bf16 slots for ln)
  //   Winb  [3072*1024]   =   6,291,456 B
  //   Woutb [1024*1024]   =   2,097,152 B
  //   qkv   [M*3072]      = 603,979,776 B   (k-slice reused as ctx,
  //                                          q-slice reused as attn_out)
  char* ws = (char*)d_ws;
  u16* Abf   = (u16*)ws;
  u16* Winb  = (u16*)(ws + 201326592);
  u16* Woutb = (u16*)(ws + 207618048);
  u16* qkv   = (u16*)(ws + 209715200);

  cvt_f32_bf16_kernel<<<2048, 256, 0, stream>>>(slots, Abf, M * 1024 / 4);
  cvt_f32_bf16_kernel<<<2048, 256, 0, stream>>>(in_w, Winb, 3072 * 1024 / 4);
  cvt_f32_bf16_kernel<<<1024, 256, 0, stream>>>(out_w, Woutb, 1024 * 1024 / 4);

  // qkv = Abf @ Winb^T + in_b : M x 3072, tiles 384 x 12
  gemm256_bt_bias<<<384 * 12, 1024, 0, stream>>>(
      Abf, Winb, in_b, qkv, 3072, 1024, 1024, 3072, 12);

  // ctx written in-place into the k-slice of qkv
  attn3_kernel<<<2048, 256, 0, stream>>>(qkv);

  // attn_out = ctx @ Woutb^T + out_b -> q-slice of qkv : M x 1024, tiles 384 x 4
  gemm256_bt_bias<<<384 * 4, 1024, 0, stream>>>(
      qkv + 1024, Woutb, out_b, qkv, 1024, 1024, 3072, 3072, 4);

  // out = LN(slots_bf16 + attn_out) * g + b
  ln_kernel<<<M / 4, 256, 0, stream>>>(Abf, qkv, ln_g, ln_b, out);
}

// Round 12
// 1288.950 us; speedup vs baseline: 1.1171x; 1.0912x over previous
//
#include <hip/hip_runtime.h>
#include <stdint.h>

typedef unsigned short u16;
typedef float f32x4 __attribute__((ext_vector_type(4)));
typedef short bf16x8 __attribute__((ext_vector_type(8)));

// ---------- helpers ----------
__device__ __forceinline__ u16 f2bu(float f) {           // fp32 -> bf16 (RNE)
  uint32_t x = __builtin_bit_cast(uint32_t, f);
  x += 0x7fffu + ((x >> 16) & 1u);
  return (u16)(x >> 16);
}
__device__ __forceinline__ float b2f(u16 u) {            // bf16 -> fp32 (exact)
  return __builtin_bit_cast(float, (uint32_t)u << 16);
}
__device__ __forceinline__ void gll16(const void* g, void* l) {
  __builtin_amdgcn_global_load_lds(
      (const __attribute__((address_space(1))) void*)g,
      (__attribute__((address_space(3))) void*)l, 16, 0, 0);
}

// ---------- fp32 -> bf16 convert ----------
__global__ __launch_bounds__(256) void cvt_f32_bf16_kernel(
    const float* __restrict__ in, u16* __restrict__ out, int n4) {
  int i = blockIdx.x * 256 + threadIdx.x;
  const int stride = gridDim.x * 256;
  for (; i < n4; i += stride) {
    float4 f = reinterpret_cast<const float4*>(in)[i];
    ushort4 o;
    o.x = f2bu(f.x); o.y = f2bu(f.y); o.z = f2bu(f.z); o.w = f2bu(f.w);
    reinterpret_cast<ushort4*>(out)[i] = o;
  }
}

// ---------- 256x256 GEMM, 16 waves, wave-tile 64x64, BK=64 per barrier ----
// C[m,n] = sum_k A[m,k]*B[n,k] + bias[n], bf16 in/out, fp32 accum.
// LDS tile [256 rows][64 cols] u16 per matrix; each row = 8 slots of 16B.
// Both-sides involution (rule #21): slot3' = slot3 ^ (row&7).
//   staging source: c8 = (tid&7) ^ ((tid>>3)&7)  (row&7 invariant under the
//   +128-row second slot); read: slot3 = ((kh<<2)|kg) ^ (fr&7)  (row&7 ==
//   fr&7 since mi*16 / w*64 / +128 are multiples of 8).
// Bank math: 8 lanes per 4-bank group x 16B = the 8-cyc minimum -> no
// conflicts. STAGE dest: slot s=tid -> u16 s*8 -> wave base wid*512 (r11 bug
// was wid*1024, which scrambled LDS -> absmax 18.5). Two k-sub rounds per
// barrier region: round 1's ds_reads are independent of round 0's MFMAs ->
// fine-grained lgkmcnt overlap with NO barrier between (halves barrier count).
__global__ __launch_bounds__(1024, 4) void gemm256_bt_bias(
    const u16* __restrict__ A, const u16* __restrict__ Bw,
    const float* __restrict__ bias, u16* __restrict__ C,
    int N, int K, int lda, int ldc, int ntn) {
  __shared__ u16 lds[2][2][16384];   // [buf][A=0/B=1][256 rows * 64 cols]
  const int tid = threadIdx.x;
  const int lane = tid & 63, wid = tid >> 6;   // wid 0..15
  const int wr = wid >> 2, wc = wid & 3;        // wave grid 4 (M) x 4 (N)
  const int fr = lane & 15, kg = lane >> 4;

  // XCD-aware swizzle (grid % 8 == 0 for both calls)
  const int cpx = (int)gridDim.x >> 3;
  const int bid = blockIdx.x;
  const int sid = (bid & 7) * cpx + (bid >> 3);
  const int mt = sid / ntn, nt = sid % ntn;

  // staging: slot s in {tid, tid+1024}; row = s>>3, slot3 = s&7.
  const int srow = tid >> 3;                    // 0..127 (slot 2 adds 128)
  const int sc8 = (tid & 7) ^ (srow & 7);
  const u16* Ag = A + (size_t)(mt * 256 + srow) * lda + sc8 * 8;
  const u16* Bg = Bw + (size_t)(nt * 256 + srow) * K + sc8 * 8;
  const size_t arstep = (size_t)128 * lda;     // +128 rows for slot 2
  const size_t brstep = (size_t)128 * K;

  // fragment read bases (u16, row stride 64); slot3 XOR per (kh,kg)
  const int fx = fr & 7;
  const int aoff = (wr * 64 + fr) * 64;         // + mi*1024 + slot3*8
  const int boff = (wc * 64 + fr) * 64;         // + nj*1024 + slot3*8

  f32x4 acc[4][4];
#pragma unroll
  for (int i = 0; i < 4; i++)
#pragma unroll
    for (int j = 0; j < 4; j++) acc[i][j] = f32x4{0.f, 0.f, 0.f, 0.f};

  const int NT = K >> 6;

#define STAGE(b, kt) do {                                                  \
    const u16* a_ = Ag + (size_t)(kt) * 64;                                \
    const u16* b_ = Bg + (size_t)(kt) * 64;                                \
    gll16(a_,          &lds[(b)][0][wid * 512]);                           \
    gll16(a_ + arstep, &lds[(b)][0][8192 + wid * 512]);                    \
    gll16(b_,          &lds[(b)][1][wid * 512]);                           \
    gll16(b_ + brstep, &lds[(b)][1][8192 + wid * 512]);                    \
  } while (0)

  STAGE(0, 0);
  __syncthreads();              // tile 0 landed (vmcnt(0) drain)

  for (int t = 0; t < NT; t++) {
    const int cur = t & 1;
    if (t + 1 < NT) STAGE(cur ^ 1, t + 1);   // prefetch next tile
    const u16* As = &lds[cur][0][0];
    const u16* Bs = &lds[cur][1][0];
#pragma unroll
    for (int kh = 0; kh < 2; kh++) {         // two k-sub rounds, no barrier
      const int slot3 = ((kh << 2) | kg) ^ fx;
      bf16x8 a[4], b[4];
#pragma unroll
      for (int nj = 0; nj < 4; nj++)
        b[nj] = *(const bf16x8*)&Bs[boff + nj * 1024 + slot3 * 8];
#pragma unroll
      for (int mi = 0; mi < 4; mi++)
        a[mi] = *(const bf16x8*)&As[aoff + mi * 1024 + slot3 * 8];
      __builtin_amdgcn_s_setprio(1);
#pragma unroll
      for (int mi = 0; mi < 4; mi++)
#pragma unroll
        for (int nj = 0; nj < 4; nj++)
          acc[mi][nj] = __builtin_amdgcn_mfma_f32_16x16x32_bf16(
              a[mi], b[nj], acc[mi][nj], 0, 0, 0);
      __builtin_amdgcn_s_setprio(0);
    }
    __syncthreads();   // next tile landed + this tile's reads done (WAR safe)
  }
#undef STAGE

  // C/D layout per 16x16 frag: col = lane&15, row = (lane>>4)*4 + reg
  const int crow0 = mt * 256 + wr * 64 + kg * 4;
  const int ccol0 = nt * 256 + wc * 64 + fr;
#pragma unroll
  for (int nj = 0; nj < 4; nj++) {
    const int col = ccol0 + nj * 16;
    const float bb = bias[col];
#pragma unroll
    for (int mi = 0; mi < 4; mi++) {
      const int r0 = crow0 + mi * 16;
      f32x4 v = acc[mi][nj];
#pragma unroll
      for (int r = 0; r < 4; r++)
        C[(size_t)(r0 + r) * ldc + col] = f2bu(v[r] + bb);
    }
  }
}

// ---------- tiny attention: S=3, 16 heads of d=64 (grid-stride) ----------
// Writes ctx IN-PLACE into the k-slice (cols 1024..2047) of qkv.
__global__ __launch_bounds__(256) void attn3_kernel(
    u16* __restrict__ qkv) {
  const int tid = threadIdx.x;
  const int lane = tid & 63, wid = tid >> 6;
  const int nunit = 32768 * 4;
  for (int unit = blockIdx.x * 4 + wid; unit < nunit; unit += gridDim.x * 4) {
    const int b = unit >> 2, hg = unit & 3;
    const size_t qbase = (size_t)b * 3 * 3072 + hg * 256 + lane * 4;

    float q[3][4], k[3][4], v[3][4];
#pragma unroll
    for (int s = 0; s < 3; s++) {
      ushort4 uq = *(const ushort4*)(qkv + qbase + (size_t)s * 3072);
      ushort4 uk = *(const ushort4*)(qkv + qbase + (size_t)s * 3072 + 1024);
      ushort4 uv = *(const ushort4*)(qkv + qbase + (size_t)s * 3072 + 2048);
      q[s][0] = b2f(uq.x); q[s][1] = b2f(uq.y); q[s][2] = b2f(uq.z); q[s][3] = b2f(uq.w);
      k[s][0] = b2f(uk.x); k[s][1] = b2f(uk.y); k[s][2] = b2f(uk.z); k[s][3] = b2f(uk.w);
      v[s][0] = b2f(uv.x); v[s][1] = b2f(uv.y); v[s][2] = b2f(uv.z); v[s][3] = b2f(uv.w);
    }

    float sc[3][3];
#pragma unroll
    for (int i = 0; i < 3; i++)
#pragma unroll
      for (int j = 0; j < 3; j++) {
        float p = q[i][0] * k[j][0] + q[i][1] * k[j][1] +
                  q[i][2] * k[j][2] + q[i][3] * k[j][3];
        p += __shfl_xor(p, 1);
        p += __shfl_xor(p, 2);
        p += __shfl_xor(p, 4);
        p += __shfl_xor(p, 8);   // 16-lane group = one head's 64 dims
        sc[i][j] = p;
      }

    float o[3][4];
#pragma unroll
    for (int i = 0; i < 3; i++) {
      float mx = fmaxf(sc[i][0], fmaxf(sc[i][1], sc[i][2]));
      float e0 = __expf((sc[i][0] - mx) * 0.125f);
      float e1 = __expf((sc[i][1] - mx) * 0.125f);
      float e2 = __expf((sc[i][2] - mx) * 0.125f);
      float inv = 1.f / (e0 + e1 + e2);
      e0 *= inv; e1 *= inv; e2 *= inv;
#pragma unroll
      for (int d = 0; d < 4; d++)
        o[i][d] = e0 * v[0][d] + e1 * v[1][d] + e2 * v[2][d];
    }

#pragma unroll
    for (int i = 0; i < 3; i++) {
      ushort4 ov;
      ov.x = f2bu(o[i][0]); ov.y = f2bu(o[i][1]);
      ov.z = f2bu(o[i][2]); ov.w = f2bu(o[i][3]);
      *(ushort4*)(qkv + qbase + (size_t)i * 3072 + 1024) = ov;
    }
  }
}

// ---------- residual + LayerNorm: wave per row of 1024 ----------
__global__ __launch_bounds__(256) void ln_kernel(
    const u16* __restrict__ slots_bf, const u16* __restrict__ ao,
    const float* __restrict__ g, const float* __restrict__ bvec,
    float* __restrict__ out) {
  const int tid = threadIdx.x;
  const int lane = tid & 63, wid = tid >> 6;
  const int row = blockIdx.x * 4 + wid;
  const size_t rb = (size_t)row * 1024;
  const size_t ab = (size_t)row * 3072;

  float y[16];
  float sum = 0.f, sq = 0.f;
#pragma unroll
  for (int c = 0; c < 4; c++) {
    const int col = c * 256 + lane * 4;
    ushort4 s4 = *(const ushort4*)(slots_bf + rb + col);
    ushort4 a4 = *(const ushort4*)(ao + ab + col);
    float y0 = b2f(s4.x) + b2f(a4.x), y1 = b2f(s4.y) + b2f(a4.y);
    float y2 = b2f(s4.z) + b2f(a4.z), y3 = b2f(s4.w) + b2f(a4.w);
    y[c * 4 + 0] = y0; y[c * 4 + 1] = y1; y[c * 4 + 2] = y2; y[c * 4 + 3] = y3;
    sum += y0 + y1 + y2 + y3;
    sq += y0 * y0 + y1 * y1 + y2 * y2 + y3 * y3;
  }
#pragma unroll
  for (int m = 1; m < 64; m <<= 1) {
    sum += __shfl_xor(sum, m);
    sq  += __shfl_xor(sq, m);
  }
  const float mu = sum * (1.0f / 1024.0f);
  const float var = sq * (1.0f / 1024.0f) - mu * mu;
  const float rs = rsqrtf(var + 1e-5f);
#pragma unroll
  for (int c = 0; c < 4; c++) {
    const int col = c * 256 + lane * 4;
    float4 gg = *(const float4*)(g + col);
    float4 bb = *(const float4*)(bvec + col);
    float4 ov;
    ov.x = (y[c * 4 + 0] - mu) * rs * gg.x + bb.x;
    ov.y = (y[c * 4 + 1] - mu) * rs * gg.y + bb.y;
    ov.z = (y[c * 4 + 2] - mu) * rs * gg.z + bb.z;
    ov.w = (y[c * 4 + 3] - mu) * rs * gg.w + bb.w;
    *(float4*)(out + rb + col) = ov;
  }
}

extern "C" void kernel_launch(void* const* d_in, const int* in_sizes, int n_in,
                              void* d_out, int out_size, void* d_ws, size_t ws_size,
                              hipStream_t stream) {
  const float* slots = (const float*)d_in[0];
  const float* in_w  = (const float*)d_in[1];
  const float* in_b  = (const float*)d_in[2];
  const float* out_w = (const float*)d_in[3];
  const float* out_b = (const float*)d_in[4];
  const float* ln_g  = (const float*)d_in[5];
  const float* ln_b  = (const float*)d_in[6];
  float* out = (float*)d_out;

  const int M = 32768 * 3;  // 98304 rows

  // workspace layout:
  //   Abf   [M*1024 bf16] = 201,326,592 B   (stays live: bf16 slots for ln)
  //   Winb  [3072*1024]   =   6,291,456 B
  //   Woutb [1024*1024]   =   2,097,152 B
  //   qkv   [M*3072]      = 603,979,776 B   (k-slice reused as ctx,
  //                                          q-slice reused as attn_out)
  char* ws = (char*)d_ws;
  u16* Abf   = (u16*)ws;
  u16* Winb  = (u16*)(ws + 201326592);
  u16* Woutb = (u16*)(ws + 207618048);
  u16* qkv   = (u16*)(ws + 209715200);

  cvt_f32_bf16_kernel<<<2048, 256, 0, stream>>>(slots, Abf, M * 1024 / 4);
  cvt_f32_bf16_kernel<<<2048, 256, 0, stream>>>(in_w, Winb, 3072 * 1024 / 4);
  cvt_f32_bf16_kernel<<<1024, 256, 0, stream>>>(out_w, Woutb, 1024 * 1024 / 4);

  // qkv = Abf @ Winb^T + in_b : M x 3072, tiles 384 x 12
  gemm256_bt_bias<<<384 * 12, 1024, 0, stream>>>(
      Abf, Winb, in_b, qkv, 3072, 1024, 1024, 3072, 12);

  // ctx written in-place into the k-slice of qkv
  attn3_kernel<<<2048, 256, 0, stream>>>(qkv);

  // attn_out = ctx @ Woutb^T + out_b -> q-slice of qkv : M x 1024, tiles 384 x 4
  gemm256_bt_bias<<<384 * 4, 1024, 0, stream>>>(
      qkv + 1024, Woutb, out_b, qkv, 1024, 1024, 3072, 3072, 4);

  // out = LN(slots_bf16 + attn_out) * g + b
  ln_kernel<<<M / 4, 256, 0, stream>>>(Abf, qkv, ln_g, ln_b, out);
}